// Round 1
// baseline (1484.372 us; speedup 1.0000x reference)
//
#include <hip/hip_runtime.h>

#define B_ 1024
#define N_ 64
#define T_ 256
#define FB_ 5
#define T2_ 128
#define C_ 128  // 2N

__device__ __forceinline__ float leaky(float x) { return x >= 0.f ? x : 0.01f * x; }
__device__ __forceinline__ float sigm(float x) { return 1.f / (1.f + expf(-x)); }

// ---------------- norm_adj: Hn = D^-1/2 (A*(1-I)+I) D^-1/2 ----------------
__global__ void knorm(const float* __restrict__ A, float* __restrict__ Hn) {
  __shared__ float Hs[64][65];
  __shared__ float dinv[64];
  int b = blockIdx.x, t = threadIdx.x;
  const float* Ab = A + (size_t)b * 4096;
  for (int i = 0; i < 64; ++i) {
    float v = Ab[i * 64 + t];
    Hs[i][t] = (i == t) ? 1.f : v;
  }
  __syncthreads();
  float s = 0.f;
  for (int j = 0; j < 64; ++j) s += Hs[t][j];
  dinv[t] = 1.f / sqrtf(s);
  __syncthreads();
  float dt = dinv[t];
  float* Hb = Hn + (size_t)b * 4096;
  for (int i = 0; i < 64; ++i) Hb[i * 64 + t] = dinv[i] * Hs[i][t] * dt;
}

// ------------- Xc+transpose: Xp[b][t][i] = leaky(w * sum_j Hn[b][i][j]*X[b][j][t]) -------------
__global__ void kxc(const float* __restrict__ Hn, const float* __restrict__ X,
                    const float* __restrict__ wsc, float* __restrict__ Xp, int S) {
  __shared__ float Hs[64][65];
  __shared__ float xs[64][65];
  int b = blockIdx.x, t0 = blockIdx.y * 64, tid = threadIdx.x;
  const float* Hb = Hn + (size_t)b * 4096;
  for (int idx = tid; idx < 4096; idx += 256) Hs[idx >> 6][idx & 63] = Hb[idx];
  const float* Xb = X + (size_t)b * 64 * S;
  for (int idx = tid; idx < 4096; idx += 256) {
    int j = idx >> 6, tt = idx & 63;
    xs[j][tt] = (t0 + tt < S) ? Xb[j * S + t0 + tt] : 0.f;
  }
  __syncthreads();
  int i = tid & 63, tg = tid >> 6;
  float w = wsc[0];
  float acc[16];
#pragma unroll
  for (int q = 0; q < 16; ++q) acc[q] = 0.f;
  for (int j = 0; j < 64; ++j) {
    float hv = Hs[i][j];
#pragma unroll
    for (int q = 0; q < 16; ++q) acc[q] += hv * xs[j][tg * 16 + q];
  }
  float* Ob = Xp + (size_t)b * S * 64;
#pragma unroll
  for (int q = 0; q < 16; ++q) {
    int t = t0 + tg * 16 + q;
    if (t < S) Ob[t * 64 + i] = leaky(w * acc[q]);
  }
}

// ---------------- fused bidirectional GRU (one direction per blockIdx.y) ----------------
// thread k owns gate-row k of both wih and whh (in VGPRs). NB=2 batches/block.
__global__ __launch_bounds__(192) void kgru(
    const float* __restrict__ Xp, int S,
    const float* __restrict__ wih_f, const float* __restrict__ whh_f,
    const float* __restrict__ bih_f, const float* __restrict__ bhh_f,
    const float* __restrict__ wih_b, const float* __restrict__ whh_b,
    const float* __restrict__ bih_b, const float* __restrict__ bhh_b,
    float* __restrict__ out) {
  __shared__ __align__(16) float h_s[2][64];
  __shared__ __align__(16) float x_s[2][2][64];  // [buf][batch][j]
  __shared__ float gx_s[2][192];
  __shared__ float gh_s[2][192];
  int tid = threadIdx.x;  // gate row k
  int dir = blockIdx.y;
  int b0 = blockIdx.x * 2;
  const float* wih = dir ? wih_b : wih_f;
  const float* whh = dir ? whh_b : whh_f;
  const float* bih = dir ? bih_b : bih_f;
  const float* bhh = dir ? bhh_b : bhh_f;
  float4 wr[16], vr[16];
#pragma unroll
  for (int q = 0; q < 16; ++q) {
    vr[q] = *(const float4*)(wih + tid * 64 + q * 4);
    wr[q] = *(const float4*)(whh + tid * 64 + q * 4);
  }
  float bihk = bih[tid], bhhk = bhh[tid];
  if (tid < 128) h_s[tid >> 6][tid & 63] = 0.f;
  int pbb = tid >> 4, pj0 = (tid & 15) * 4;
  if (tid < 32) {
    int tr = dir ? (S - 1) : 0;
    *(float4*)&x_s[0][pbb][pj0] =
        *(const float4*)(Xp + ((size_t)(b0 + pbb) * S + tr) * 64 + pj0);
  }
  for (int t = 0; t < S; ++t) {
    int cur = t & 1;
    __syncthreads();  // x_s[cur] + h_s ready for all waves
    float4 xpre;
    bool pf = (tid < 32) && (t + 1 < S);
    if (pf) {
      int tr = dir ? (S - 2 - t) : (t + 1);
      xpre = *(const float4*)(Xp + ((size_t)(b0 + pbb) * S + tr) * 64 + pj0);
    }
    float accx0 = bihk, acch0 = bhhk, accx1 = bihk, acch1 = bhhk;
    const float4* h0 = (const float4*)h_s[0];
    const float4* h1 = (const float4*)h_s[1];
    const float4* x0 = (const float4*)x_s[cur][0];
    const float4* x1 = (const float4*)x_s[cur][1];
#pragma unroll
    for (int q = 0; q < 16; ++q) {
      float4 ha = h0[q], hbv = h1[q], xa = x0[q], xbv = x1[q];
      acch0 += wr[q].x * ha.x + wr[q].y * ha.y + wr[q].z * ha.z + wr[q].w * ha.w;
      acch1 += wr[q].x * hbv.x + wr[q].y * hbv.y + wr[q].z * hbv.z + wr[q].w * hbv.w;
      accx0 += vr[q].x * xa.x + vr[q].y * xa.y + vr[q].z * xa.z + vr[q].w * xa.w;
      accx1 += vr[q].x * xbv.x + vr[q].y * xbv.y + vr[q].z * xbv.z + vr[q].w * xbv.w;
    }
    gx_s[0][tid] = accx0; gh_s[0][tid] = acch0;
    gx_s[1][tid] = accx1; gh_s[1][tid] = acch1;
    if (pf) *(float4*)&x_s[cur ^ 1][pbb][pj0] = xpre;  // write-back prefetch
    __syncthreads();
    if (tid < 128) {
      int hb = tid >> 6, j = tid & 63;
      float r = sigm(gx_s[hb][j] + gh_s[hb][j]);
      float z = sigm(gx_s[hb][j + 64] + gh_s[hb][j + 64]);
      float n = tanhf(gx_s[hb][j + 128] + r * gh_s[hb][j + 128]);
      float hn = (1.f - z) * n + z * h_s[hb][j];
      h_s[hb][j] = hn;
      int tt = dir ? (S - 1 - t) : t;
      out[((size_t)(b0 + hb) * S + tt) * 128 + dir * 64 + j] = hn;
    }
  }
}

// ---------------- BN(train) stats -> per-channel scale/shift ----------------
__global__ void kbn(const float* __restrict__ g, int S,
                    const float* __restrict__ gamma, const float* __restrict__ beta,
                    float* __restrict__ sd) {
  int t = blockIdx.x, tid = threadIdx.x;
  float s = 0.f, s2 = 0.f;
  for (int i = tid; i < B_ * C_; i += 256) {
    int b = i >> 7, c = i & 127;
    float v = g[((size_t)b * S + t) * 128 + c];
    s += v; s2 += v * v;
  }
  __shared__ float rs[256], rq[256];
  rs[tid] = s; rq[tid] = s2;
  __syncthreads();
  for (int off = 128; off; off >>= 1) {
    if (tid < off) { rs[tid] += rs[tid + off]; rq[tid] += rq[tid + off]; }
    __syncthreads();
  }
  if (tid == 0) {
    float inv_n = 1.f / (float)(B_ * C_);
    float m = rs[0] * inv_n;
    float var = rq[0] * inv_n - m * m;
    float inv = 1.f / sqrtf(var + 1e-5f);
    float sc = gamma[t] * inv;
    sd[2 * t] = sc;
    sd[2 * t + 1] = beta[t] - m * sc;
  }
}

// -------- M_T[o][t][c] = sum_t2 W1[o][16384 + c*128 + t2] * linT_w[t2][t] --------
__global__ void kMT(const float* __restrict__ W1, const float* __restrict__ lw,
                    float* __restrict__ MT) {
  __shared__ float W1s[128][129];
  __shared__ float ls[128][32];
  int o = blockIdx.x, t0 = blockIdx.y * 32, tid = threadIdx.x;
  const float* Wo = W1 + (size_t)o * 32768 + 16384;
  for (int idx = tid; idx < 16384; idx += 256) W1s[idx >> 7][idx & 127] = Wo[idx];
  for (int idx = tid; idx < 4096; idx += 256)
    ls[idx >> 5][idx & 31] = lw[(idx >> 5) * 256 + t0 + (idx & 31)];
  __syncthreads();
  int c = tid & 127, th = tid >> 7;
  float acc[16];
#pragma unroll
  for (int q = 0; q < 16; ++q) acc[q] = 0.f;
  for (int t2 = 0; t2 < 128; ++t2) {
    float w = W1s[c][t2];
#pragma unroll
    for (int q = 0; q < 16; ++q) acc[q] += w * ls[t2][th + 2 * q];
  }
  float* Mo = MT + (size_t)o * 32768;
#pragma unroll
  for (int q = 0; q < 16; ++q) Mo[(t0 + th + 2 * q) * 128 + c] = acc[q];
}

// -------- M_F[o][f][c] = sum_t2 W1[o][c*128 + t2] * linF_w[t2][f] --------
__global__ void kMF(const float* __restrict__ W1, const float* __restrict__ lw,
                    float* __restrict__ MF) {
  __shared__ float W1s[128][129];
  __shared__ float ls[128][8];
  int o = blockIdx.x, tid = threadIdx.x;
  const float* Wo = W1 + (size_t)o * 32768;
  for (int idx = tid; idx < 16384; idx += 256) W1s[idx >> 7][idx & 127] = Wo[idx];
  for (int idx = tid; idx < 640; idx += 256) ls[idx / 5][idx % 5] = lw[idx];
  __syncthreads();
  int c = tid & 127, fh = tid >> 7;
  float acc[3] = {0.f, 0.f, 0.f};
  for (int t2 = 0; t2 < 128; ++t2) {
    float w = W1s[c][t2];
#pragma unroll
    for (int q = 0; q < 3; ++q) {
      int f = fh + 2 * q;
      if (f < 5) acc[q] += w * ls[t2][f];
    }
  }
#pragma unroll
  for (int q = 0; q < 3; ++q) {
    int f = fh + 2 * q;
    if (f < 5) MF[(size_t)o * 640 + f * 128 + c] = acc[q];
  }
}

// -------- c0[o] = lin1_b[o] + sum_idx W1F*linF_b + W1T*linT_b --------
__global__ void kc0(const float* __restrict__ W1, const float* __restrict__ lFb,
                    const float* __restrict__ lTb, const float* __restrict__ l1b,
                    float* __restrict__ c0) {
  int o = blockIdx.x, tid = threadIdx.x;
  const float* Wo = W1 + (size_t)o * 32768;
  float s = 0.f;
  for (int idx = tid; idx < 16384; idx += 256) {
    int t2 = idx & 127;
    s += Wo[idx] * lFb[t2] + Wo[16384 + idx] * lTb[t2];
  }
  __shared__ float rs[256];
  rs[tid] = s;
  __syncthreads();
  for (int off = 128; off; off >>= 1) {
    if (tid < off) rs[tid] += rs[tid + off];
    __syncthreads();
  }
  if (tid == 0) c0[o] = l1b[o] + rs[0];
}

// -------- partial[slot][b][o] = sum_{t in chunk, c} (g*s_t+d_t) * M[o][t][c] --------
__global__ void kchunk(const float* __restrict__ g, int S, int nt,
                       const float* __restrict__ sd, const float* __restrict__ M,
                       float* __restrict__ part, int slot0) {
  __shared__ float gs[32][128];
  __shared__ float Ms[64 * 129];
  int tid = threadIdx.x;
  int b0 = blockIdx.x * 32;
  int t0 = blockIdx.y * nt;
  int slot = slot0 + blockIdx.y;
  int ot = tid & 31, bt = tid >> 5;
  float acc[4][2];
#pragma unroll
  for (int i = 0; i < 4; ++i) { acc[i][0] = 0.f; acc[i][1] = 0.f; }
  for (int t = t0; t < t0 + nt; ++t) {
    __syncthreads();
    float sc = sd[2 * t], dd = sd[2 * t + 1];
    for (int idx = tid; idx < 4096; idx += 256) {
      int bb = idx >> 7, c = idx & 127;
      gs[bb][c] = g[((size_t)(b0 + bb) * S + t) * 128 + c] * sc + dd;
    }
    for (int idx = tid; idx < 8192; idx += 256) {
      int o = idx >> 7, c = idx & 127;
      Ms[o * 129 + c] = M[((size_t)o * S + t) * 128 + c];
    }
    __syncthreads();
    for (int c = 0; c < 128; ++c) {
      float m0 = Ms[ot * 129 + c];
      float m1 = Ms[(ot + 32) * 129 + c];
#pragma unroll
      for (int i = 0; i < 4; ++i) {
        float gv = gs[bt * 4 + i][c];
        acc[i][0] += gv * m0;
        acc[i][1] += gv * m1;
      }
    }
  }
#pragma unroll
  for (int i = 0; i < 4; ++i) {
    part[((size_t)slot * 1024 + b0 + bt * 4 + i) * 64 + ot] = acc[i][0];
    part[((size_t)slot * 1024 + b0 + bt * 4 + i) * 64 + ot + 32] = acc[i][1];
  }
}

// -------- finalize: y = leaky(sum partials + c0); out = y @ lin2^T + b2 --------
__global__ void kfin(const float* __restrict__ part, const float* __restrict__ c0,
                     const float* __restrict__ l2w, const float* __restrict__ l2b,
                     float* __restrict__ outp) {
  int b = blockIdx.x, o = threadIdx.x;
  float y = c0[o];
  for (int s = 0; s < 17; ++s) y += part[((size_t)s * 1024 + b) * 64 + o];
  y = leaky(y);
  __shared__ float a[64];
  a[o] = y;
  __syncthreads();
  if (o < 3) {
    float r = l2b[o];
    for (int j = 0; j < 64; ++j) r += l2w[o * 64 + j] * a[j];
    outp[b * 3 + o] = r;
  }
}

extern "C" void kernel_launch(void* const* d_in, const int* in_sizes, int n_in,
                              void* d_out, int out_size, void* d_ws, size_t ws_size,
                              hipStream_t stream) {
  const float* x_T = (const float*)d_in[0];
  const float* x_F = (const float*)d_in[1];
  const float* A = (const float*)d_in[2];
  const float* gcnw_F = (const float*)d_in[3];
  const float* gFwih_f = (const float*)d_in[4];
  const float* gFwhh_f = (const float*)d_in[5];
  const float* gFbih_f = (const float*)d_in[6];
  const float* gFbhh_f = (const float*)d_in[7];
  const float* gFwih_b = (const float*)d_in[8];
  const float* gFwhh_b = (const float*)d_in[9];
  const float* gFbih_b = (const float*)d_in[10];
  const float* gFbhh_b = (const float*)d_in[11];
  const float* bnFg = (const float*)d_in[12];
  const float* bnFb = (const float*)d_in[13];
  const float* gcnw_T = (const float*)d_in[14];
  const float* gTwih_f = (const float*)d_in[15];
  const float* gTwhh_f = (const float*)d_in[16];
  const float* gTbih_f = (const float*)d_in[17];
  const float* gTbhh_f = (const float*)d_in[18];
  const float* gTwih_b = (const float*)d_in[19];
  const float* gTwhh_b = (const float*)d_in[20];
  const float* gTbih_b = (const float*)d_in[21];
  const float* gTbhh_b = (const float*)d_in[22];
  const float* bnTg = (const float*)d_in[23];
  const float* bnTb = (const float*)d_in[24];
  const float* linF_w = (const float*)d_in[25];
  const float* linF_b = (const float*)d_in[26];
  const float* linT_w = (const float*)d_in[27];
  const float* linT_b = (const float*)d_in[28];
  const float* lin1_w = (const float*)d_in[29];
  const float* lin1_b = (const float*)d_in[30];
  const float* lin2_w = (const float*)d_in[31];
  const float* lin2_b = (const float*)d_in[32];

  float* ws = (float*)d_ws;
  float* Hn  = ws;
  float* XpT = Hn + (size_t)1024 * 4096;
  float* XpF = XpT + (size_t)1024 * 256 * 64;
  float* gT  = XpF + (size_t)1024 * 5 * 64;
  float* gF  = gT + (size_t)1024 * 256 * 128;
  float* sdT = gF + (size_t)1024 * 5 * 128;
  float* sdF = sdT + 512;
  float* MT  = sdF + 16;
  float* MF  = MT + (size_t)64 * 256 * 128;
  float* c0  = MF + (size_t)64 * 5 * 128;
  float* part = c0 + 64;

  knorm<<<1024, 64, 0, stream>>>(A, Hn);
  kxc<<<dim3(1024, 4), 256, 0, stream>>>(Hn, x_T, gcnw_T, XpT, 256);
  kxc<<<dim3(1024, 1), 256, 0, stream>>>(Hn, x_F, gcnw_F, XpF, 5);
  kgru<<<dim3(512, 2), 192, 0, stream>>>(XpT, 256, gTwih_f, gTwhh_f, gTbih_f, gTbhh_f,
                                         gTwih_b, gTwhh_b, gTbih_b, gTbhh_b, gT);
  kgru<<<dim3(512, 2), 192, 0, stream>>>(XpF, 5, gFwih_f, gFwhh_f, gFbih_f, gFbhh_f,
                                         gFwih_b, gFwhh_b, gFbih_b, gFbhh_b, gF);
  kbn<<<256, 256, 0, stream>>>(gT, 256, bnTg, bnTb, sdT);
  kbn<<<5, 256, 0, stream>>>(gF, 5, bnFg, bnFb, sdF);
  kMT<<<dim3(64, 8), 256, 0, stream>>>(lin1_w, linT_w, MT);
  kMF<<<64, 256, 0, stream>>>(lin1_w, linF_w, MF);
  kc0<<<64, 256, 0, stream>>>(lin1_w, linF_b, linT_b, lin1_b, c0);
  kchunk<<<dim3(32, 16), 256, 0, stream>>>(gT, 256, 16, sdT, MT, part, 0);
  kchunk<<<dim3(32, 1), 256, 0, stream>>>(gF, 5, 5, sdF, MF, part, 16);
  kfin<<<1024, 64, 0, stream>>>(part, c0, lin2_w, lin2_b, (float*)d_out);
}